// Round 1
// baseline (458.047 us; speedup 1.0000x reference)
//
#include <hip/hip_runtime.h>
#include <hip/hip_bf16.h>
#include <math.h>
#include <stdint.h>

// TGN attention node, algebraically restructured (K/V never materialized):
//   qk[b,h,:]  = C_h . source[b] + cb_h,   C = (1/16) Wk_h^T Wq_h   (bk cancels)
//   scores     = gene . qk, softmax over s
//   gbar[b,h]  = sum_s w[h,s] gene[b,s]    (sum w = 1 absorbs bv)
//   out        = ([gbar_0|gbar_1] @ D^T + e) * gate + source,  D = Wout_h Wv_h
// Round 5: (a) drop srcb round-trip - gemm1 stages fp32 src directly (AF32
// template path), prep loses 256 conversion blocks; (b) k_attn scores via
// fp32 register dot + shfl reduce (no MFMA detour, one fewer barrier, no
// sp/msk_s LDS, ballot-based invalid detection, mask load hoisted).

#define NB 4096
#define SNB 32
#define DM 512

typedef __attribute__((ext_vector_type(8))) short bf16x8;
typedef __attribute__((ext_vector_type(4))) float f32x4;

__device__ __forceinline__ unsigned short f2bf(float f) {
    union { float f; unsigned int u; } v; v.f = f;
    unsigned int u = v.u;
    return (unsigned short)((u + 0x7FFFu + ((u >> 16) & 1u)) >> 16);
}
__device__ __forceinline__ float bf2f(unsigned short s) {
    union { unsigned int u; float f; } v; v.u = ((unsigned int)s) << 16;
    return v.f;
}

// ---------------- fused prep + C/D precompute -------------------------------
// blocks: [0] mask-dtype detect | [1,4] cb | [5,6] e
//         [7,134] C tiles (MFMA, inline transpose) | [135,262] D tiles
__global__ __launch_bounds__(256) void k_prep_cd(
    const float* __restrict__ Wq,
    const float* __restrict__ bq, const float* __restrict__ Wk,
    const float* __restrict__ Wv, const float* __restrict__ Wout,
    const float* __restrict__ bv, const float* __restrict__ bout,
    const unsigned int* __restrict__ maskw,
    float* __restrict__ cb,
    float* __restrict__ e, int* __restrict__ mode,
    unsigned short* __restrict__ C, unsigned short* __restrict__ D)
{
    __shared__ __align__(16) unsigned short As[64 * 40];
    __shared__ __align__(16) unsigned short Bs[64 * 40];
    __shared__ int fF, fH;
    int bid = blockIdx.x, t = threadIdx.x;

    if (bid == 0) {                                   // mask dtype detect
        if (t == 0) { fF = 0; fH = 0; }
        __syncthreads();
        int lf = 0, lh = 0;
        for (int i = t; i < 32768; i += 256) {        // 128KB: in-bounds u8/i32/f32
            unsigned int w = maskw[i];
            lf |= (w == 0x3F800000u);
            lh |= ((w & 0xFFFFFF00u) != 0u);
        }
        if (lf) atomicOr(&fF, 1);
        if (lh) atomicOr(&fH, 1);
        __syncthreads();
        if (t == 0) *mode = fF ? 2 : (fH ? 1 : 0);
        return;
    }
    if (bid <= 4) {                                   // cb[h*512+j] = Wk^T bq / 16
        int idx = (bid - 1) * 256 + t;
        int h = idx >> 9, j = idx & 511;
        float a = 0.f;
        for (int i = 0; i < 256; i++)
            a += Wk[(size_t)(h * 256 + i) * 512 + j] * bq[h * 256 + i];
        cb[idx] = 0.0625f * a;
        return;
    }
    if (bid <= 6) {                                   // e[n] = Wout.bv + bout
        int n = (bid - 5) * 256 + t;
        const float4* wr = (const float4*)(Wout + (size_t)n * 512);
        const float4* bv4 = (const float4*)bv;
        float a = bout[n];
        for (int q = 0; q < 128; q++) {
            float4 wv = wr[q], vv = bv4[q];
            a += wv.x * vv.x + wv.y * vv.y + wv.z * vv.z + wv.w * vv.w;
        }
        e[n] = a;
        return;
    }

    // ---- C/D 64x64 MFMA tiles, K=256 (per-head), transpose during staging --
    int w = t >> 6, l = t & 63;
    int wm = (w >> 1) << 5, wn = (w & 1) << 5;
    int quad = l >> 4, lm = l & 15;
    int sj = t & 63, si8 = (t >> 6) << 3;             // transpose-staging map
    f32x4 acc00 = {0.f,0.f,0.f,0.f}, acc01 = {0.f,0.f,0.f,0.f};
    f32x4 acc10 = {0.f,0.f,0.f,0.f}, acc11 = {0.f,0.f,0.f,0.f};

    unsigned short* outp;
    int ldo;
    if (bid < 135) {                                  // C[j0..][m0..]
        int tt = bid - 7;
        int j0 = (tt >> 3) << 6, m0 = (tt & 7) << 6;
        int jc = j0 & 511;                            // Wk column (per-head j)
        int ib = (j0 >> 9) << 8;                      // head i-range base
        for (int ic = 0; ic < 8; ic++) {
            int i0 = ib + ic * 32;
            bf16x8 av, bw;
#pragma unroll
            for (int q = 0; q < 8; q++) {             // coalesced row-segment loads
                av[q] = (short)f2bf(Wk[(size_t)(i0 + si8 + q) * 512 + jc + sj] * 0.0625f);
                bw[q] = (short)f2bf(Wq[(size_t)(i0 + si8 + q) * 512 + m0 + sj]);
            }
            *(bf16x8*)(As + sj * 40 + si8) = av;      // transposed, conflict-free b128
            *(bf16x8*)(Bs + sj * 40 + si8) = bw;
            __syncthreads();
            bf16x8 a0 = *(const bf16x8*)(As + (wm + lm) * 40 + quad * 8);
            bf16x8 a1 = *(const bf16x8*)(As + (wm + 16 + lm) * 40 + quad * 8);
            bf16x8 b0 = *(const bf16x8*)(Bs + (wn + lm) * 40 + quad * 8);
            bf16x8 b1 = *(const bf16x8*)(Bs + (wn + 16 + lm) * 40 + quad * 8);
            acc00 = __builtin_amdgcn_mfma_f32_16x16x32_bf16(a0, b0, acc00, 0, 0, 0);
            acc01 = __builtin_amdgcn_mfma_f32_16x16x32_bf16(a0, b1, acc01, 0, 0, 0);
            acc10 = __builtin_amdgcn_mfma_f32_16x16x32_bf16(a1, b0, acc10, 0, 0, 0);
            acc11 = __builtin_amdgcn_mfma_f32_16x16x32_bf16(a1, b1, acc11, 0, 0, 0);
            __syncthreads();
        }
        outp = C + (size_t)j0 * 512 + m0; ldo = 512;
    } else {                                          // D[n0..][jh0..]
        int tt = bid - 135;
        int n0 = (tt >> 4) << 6, jh0 = (tt & 15) << 6;
        int jc0 = jh0 & 511;
        int ib = (jh0 >> 9) << 8;
        int ra = t >> 2, ca = (t & 3) << 3;           // direct-staging map (A)
        for (int ic = 0; ic < 8; ic++) {
            int i0 = ib + ic * 32;
            {                                         // A = Wout rows (no transpose)
                const float4* p = (const float4*)(Wout + (size_t)(n0 + ra) * 512 + i0 + ca);
                float4 v0 = p[0], v1 = p[1];
                bf16x8 av;
                av[0] = (short)f2bf(v0.x); av[1] = (short)f2bf(v0.y);
                av[2] = (short)f2bf(v0.z); av[3] = (short)f2bf(v0.w);
                av[4] = (short)f2bf(v1.x); av[5] = (short)f2bf(v1.y);
                av[6] = (short)f2bf(v1.z); av[7] = (short)f2bf(v1.w);
                *(bf16x8*)(As + ra * 40 + ca) = av;
            }
            bf16x8 bw;
#pragma unroll
            for (int q = 0; q < 8; q++)               // B = Wv^T via transpose staging
                bw[q] = (short)f2bf(Wv[(size_t)(i0 + si8 + q) * 512 + jc0 + sj]);
            *(bf16x8*)(Bs + sj * 40 + si8) = bw;
            __syncthreads();
            bf16x8 a0 = *(const bf16x8*)(As + (wm + lm) * 40 + quad * 8);
            bf16x8 a1 = *(const bf16x8*)(As + (wm + 16 + lm) * 40 + quad * 8);
            bf16x8 b0 = *(const bf16x8*)(Bs + (wn + lm) * 40 + quad * 8);
            bf16x8 b1 = *(const bf16x8*)(Bs + (wn + 16 + lm) * 40 + quad * 8);
            acc00 = __builtin_amdgcn_mfma_f32_16x16x32_bf16(a0, b0, acc00, 0, 0, 0);
            acc01 = __builtin_amdgcn_mfma_f32_16x16x32_bf16(a0, b1, acc01, 0, 0, 0);
            acc10 = __builtin_amdgcn_mfma_f32_16x16x32_bf16(a1, b0, acc10, 0, 0, 0);
            acc11 = __builtin_amdgcn_mfma_f32_16x16x32_bf16(a1, b1, acc11, 0, 0, 0);
            __syncthreads();
        }
        outp = D + (size_t)n0 * 1024 + jh0; ldo = 1024;
    }
    f32x4 accs[2][2] = {{acc00, acc01}, {acc10, acc11}};
    for (int ms = 0; ms < 2; ms++)
        for (int ns = 0; ns < 2; ns++)
            for (int r = 0; r < 4; r++)
                outp[(size_t)(wm + ms * 16 + quad * 4 + r) * ldo + wn + ns * 16 + lm] =
                    f2bf(accs[ms][ns][r]);
}

// ---------------- MFMA GEMM, B^T layout, BK=64: out[m,n]=sum_k A[m,k]Bt[n,k]
// AF32 1: A is fp32, converted to bf16 during staging (no srcb round-trip)
// EPI 0: bf16 out = acc + bias[n]  (QK)
// EPI 1: f32 out = (acc + bias[n]) * gscale[m] + resid[m,n]  (final)
template <int EPI, int AF32>
__global__ __launch_bounds__(256) void k_gemm_bt(
    const void* __restrict__ Ap, const unsigned short* __restrict__ Bt,
    void* __restrict__ outp, const float* __restrict__ bias,
    const float* __restrict__ gscale, const float* __restrict__ resid,
    int M, int N, int K)
{
    __shared__ __align__(16) unsigned short As[2][64 * 40];
    __shared__ __align__(16) unsigned short Bs[2][64 * 40];
    int nt = N >> 6;
    int m0 = ((int)blockIdx.x / nt) << 6;
    int n0 = ((int)blockIdx.x % nt) << 6;
    int t = threadIdx.x;
    int w = t >> 6, l = t & 63;
    int wm = (w >> 1) << 5, wn = (w & 1) << 5;
    int quad = l >> 4, lm = l & 15;

    f32x4 acc00 = {0.f,0.f,0.f,0.f}, acc01 = {0.f,0.f,0.f,0.f};
    f32x4 acc10 = {0.f,0.f,0.f,0.f}, acc11 = {0.f,0.f,0.f,0.f};

    int srow = t >> 2, spart = t & 3;
    int chunk = spart >> 1, coff = (spart & 1) << 4;
    const unsigned short* ag =
        (const unsigned short*)Ap + (size_t)(m0 + srow) * K + spart * 16;
    const float4* agf =
        (const float4*)((const float*)Ap + (size_t)(m0 + srow) * K) + spart * 4;
    const unsigned short* bg = Bt + (size_t)(n0 + srow) * K + spart * 16;
    unsigned short* asl = &As[chunk][srow * 40 + coff];
    unsigned short* bsl = &Bs[chunk][srow * 40 + coff];

    for (int k0 = 0; k0 < K; k0 += 64) {
        if (AF32) {
            float4 x0 = agf[0], x1 = agf[1], x2 = agf[2], x3 = agf[3];
            bf16x8 u0, u1;
            u0[0] = (short)f2bf(x0.x); u0[1] = (short)f2bf(x0.y);
            u0[2] = (short)f2bf(x0.z); u0[3] = (short)f2bf(x0.w);
            u0[4] = (short)f2bf(x1.x); u0[5] = (short)f2bf(x1.y);
            u0[6] = (short)f2bf(x1.z); u0[7] = (short)f2bf(x1.w);
            u1[0] = (short)f2bf(x2.x); u1[1] = (short)f2bf(x2.y);
            u1[2] = (short)f2bf(x2.z); u1[3] = (short)f2bf(x2.w);
            u1[4] = (short)f2bf(x3.x); u1[5] = (short)f2bf(x3.y);
            u1[6] = (short)f2bf(x3.z); u1[7] = (short)f2bf(x3.w);
            *(bf16x8*)asl       = u0;
            *(bf16x8*)(asl + 8) = u1;
            agf += 16;
        } else {
            *(bf16x8*)asl       = *(const bf16x8*)ag;
            *(bf16x8*)(asl + 8) = *(const bf16x8*)(ag + 8);
            ag += 64;
        }
        *(bf16x8*)bsl       = *(const bf16x8*)bg;
        *(bf16x8*)(bsl + 8) = *(const bf16x8*)(bg + 8);
        bg += 64;
        __syncthreads();
#pragma unroll
        for (int c = 0; c < 2; c++) {
            bf16x8 a0 = *(const bf16x8*)(&As[c][(wm + lm) * 40 + quad * 8]);
            bf16x8 a1 = *(const bf16x8*)(&As[c][(wm + 16 + lm) * 40 + quad * 8]);
            bf16x8 b0 = *(const bf16x8*)(&Bs[c][(wn + lm) * 40 + quad * 8]);
            bf16x8 b1 = *(const bf16x8*)(&Bs[c][(wn + 16 + lm) * 40 + quad * 8]);
            acc00 = __builtin_amdgcn_mfma_f32_16x16x32_bf16(a0, b0, acc00, 0, 0, 0);
            acc01 = __builtin_amdgcn_mfma_f32_16x16x32_bf16(a0, b1, acc01, 0, 0, 0);
            acc10 = __builtin_amdgcn_mfma_f32_16x16x32_bf16(a1, b0, acc10, 0, 0, 0);
            acc11 = __builtin_amdgcn_mfma_f32_16x16x32_bf16(a1, b1, acc11, 0, 0, 0);
        }
        __syncthreads();
    }
    f32x4 accs[2][2] = {{acc00, acc01}, {acc10, acc11}};
    for (int ms = 0; ms < 2; ms++) {
        for (int ns = 0; ns < 2; ns++) {
            int n = n0 + wn + ns * 16 + lm;
            float bval = bias[n];
            for (int r = 0; r < 4; r++) {
                int m = m0 + wm + ms * 16 + quad * 4 + r;
                float v = accs[ms][ns][r] + bval;
                if (EPI == 0) {
                    ((unsigned short*)outp)[(size_t)m * N + n] = f2bf(v);
                } else {
                    ((float*)outp)[(size_t)m * N + n] =
                        v * gscale[m] + resid[(size_t)m * N + n];
                }
            }
        }
    }
}

// ---------------- fused per-row attention -----------------------------------
// scores in fp32 from the gene registers (fused with bf16 LDS staging),
// 64-lane shfl reduce; ballot-based invalid-row handling; PV from LDS.
__global__ __launch_bounds__(256) void k_attn(
    const float* __restrict__ gene, const unsigned short* __restrict__ QKb,
    const void* __restrict__ maskbuf, const int* __restrict__ modep,
    const float* __restrict__ mask_n,
    unsigned short* __restrict__ G, float* __restrict__ gscale,
    float* __restrict__ aw_out)
{
    __shared__ __align__(16) unsigned short glb[32 * 520];
    __shared__ float sc[64];                          // [h*32 + s]
    __shared__ float wls[64];

    int b = blockIdx.x, t = threadIdx.x;
    int w = t >> 6, l = t & 63;

    // hoisted mask load (latency hides under gene loads)
    int mode = *modep;
    int mk = 0;
    if (t < 64) {
        size_t moff = (size_t)b * 32 + (t & 31);
        if (mode == 1)      mk = ((const unsigned char*)maskbuf)[moff] != 0;
        else if (mode == 2) mk = (((const float*)maskbuf)[moff] != 0.0f);
        else                mk = (((const int*)maskbuf)[moff] != 0);
    }

    // qk slice for my j-range: j = l*8 .. l*8+7, both heads, bf16 -> f32
    float qv0[8], qv1[8];
    {
        const ushort4* qp = (const ushort4*)(QKb + (size_t)b * 1024) + l * 2;
        ushort4 a0 = qp[0], a1 = qp[1];               // h=0
        ushort4 c0 = qp[128], c1 = qp[129];           // h=1 (+512 shorts)
        qv0[0] = bf2f(a0.x); qv0[1] = bf2f(a0.y); qv0[2] = bf2f(a0.z); qv0[3] = bf2f(a0.w);
        qv0[4] = bf2f(a1.x); qv0[5] = bf2f(a1.y); qv0[6] = bf2f(a1.z); qv0[7] = bf2f(a1.w);
        qv1[0] = bf2f(c0.x); qv1[1] = bf2f(c0.y); qv1[2] = bf2f(c0.z); qv1[3] = bf2f(c0.w);
        qv1[4] = bf2f(c1.x); qv1[5] = bf2f(c1.y); qv1[6] = bf2f(c1.z); qv1[7] = bf2f(c1.w);
    }

    // stage gene -> LDS bf16, fused fp32 score dot; wave w, iter it -> s=w+4*it
    const float4* gp = (const float4*)(gene + (size_t)b * (SNB * DM));
#pragma unroll
    for (int it = 0; it < 8; it++) {
        float4 v0 = gp[t * 2 + it * 512];
        float4 v1 = gp[t * 2 + 1 + it * 512];
        int s = w + it * 4;
        bf16x8 pk;
        pk[0] = (short)f2bf(v0.x); pk[1] = (short)f2bf(v0.y);
        pk[2] = (short)f2bf(v0.z); pk[3] = (short)f2bf(v0.w);
        pk[4] = (short)f2bf(v1.x); pk[5] = (short)f2bf(v1.y);
        pk[6] = (short)f2bf(v1.z); pk[7] = (short)f2bf(v1.w);
        *(bf16x8*)(glb + s * 520 + l * 8) = pk;
        float p0 = v0.x * qv0[0] + v0.y * qv0[1] + v0.z * qv0[2] + v0.w * qv0[3]
                 + v1.x * qv0[4] + v1.y * qv0[5] + v1.z * qv0[6] + v1.w * qv0[7];
        float p1 = v0.x * qv1[0] + v0.y * qv1[1] + v0.z * qv1[2] + v0.w * qv1[3]
                 + v1.x * qv1[4] + v1.y * qv1[5] + v1.z * qv1[6] + v1.w * qv1[7];
        for (int off = 32; off > 0; off >>= 1) {
            p0 += __shfl_xor(p0, off, 64);
            p1 += __shfl_xor(p1, off, 64);
        }
        if (l == 0) { sc[s] = p0; sc[32 + s] = p1; }
    }
    __syncthreads();

    // softmax (wave 0: lanes 0..31 = h0, 32..63 = h1; same s pattern per half)
    if (t < 64) {
        unsigned long long bal = __ballot(mk != 0);
        int invalid = (bal == 0xFFFFFFFFFFFFFFFFull);
        if (invalid && (t & 31) == 0) mk = 0;         // unmask slot 0
        float v = sc[t];
        float vm = mk ? -1e30f : v;
        for (int off = 16; off > 0; off >>= 1) vm = fmaxf(vm, __shfl_xor(vm, off, 64));
        float ex = mk ? 0.0f : __expf(v - vm);
        float sm = ex;
        for (int off = 16; off > 0; off >>= 1) sm += __shfl_xor(sm, off, 64);
        wls[t] = ex / sm;
        if (t == 0) gscale[b] = invalid ? 0.0f : mask_n[b];
    }
    __syncthreads();

    if (t < 32) aw_out[(size_t)b * 32 + t] = 0.5f * (wls[t] + wls[32 + t]);

    // PV: gbar[h, jg..jg+3] = sum_s w[h,s] * gene[s, jg..jg+3]
    {
        int h = t >> 7, jg = (t & 127) << 2;
        float a0 = 0.f, a1 = 0.f, a2 = 0.f, a3 = 0.f;
        const float* wrow = wls + h * 32;
        for (int s4 = 0; s4 < 8; s4++) {
            float4 wv = *(const float4*)(wrow + s4 * 4);
#pragma unroll
            for (int si = 0; si < 4; si++) {
                int s = s4 * 4 + si;
                ushort4 gv = *(const ushort4*)(glb + s * 520 + jg);
                float wq = (si == 0) ? wv.x : (si == 1) ? wv.y : (si == 2) ? wv.z : wv.w;
                a0 += wq * bf2f(gv.x); a1 += wq * bf2f(gv.y);
                a2 += wq * bf2f(gv.z); a3 += wq * bf2f(gv.w);
            }
        }
        ushort4 ov;
        ov.x = f2bf(a0); ov.y = f2bf(a1); ov.z = f2bf(a2); ov.w = f2bf(a3);
        *(ushort4*)(G + (size_t)b * 1024 + h * 512 + jg) = ov;
    }
}

extern "C" void kernel_launch(void* const* d_in, const int* in_sizes, int n_in,
                              void* d_out, int out_size, void* d_ws, size_t ws_size,
                              hipStream_t stream)
{
    const float* src   = (const float*)d_in[0];
    const float* gene  = (const float*)d_in[1];
    const void*  mask  = d_in[2];
    const float* maskn = (const float*)d_in[3];
    const float* Wq    = (const float*)d_in[4];
    const float* bq    = (const float*)d_in[5];
    const float* Wk    = (const float*)d_in[6];
    // d_in[7] = bk: cancels in softmax, unused
    const float* Wv    = (const float*)d_in[8];
    const float* bv    = (const float*)d_in[9];
    const float* Wout  = (const float*)d_in[10];
    const float* bout  = (const float*)d_in[11];

    float* out = (float*)d_out;
    float* aw  = out + (size_t)NB * DM;

    char* ws = (char*)d_ws;
    size_t off = 0;
    auto alloc = [&](size_t bytes) -> void* {
        void* p = ws + off;
        off = (off + bytes + 255) & ~((size_t)255);
        return p;
    };
    int* mode            = (int*)alloc(4);
    unsigned short* Cb   = (unsigned short*)alloc((size_t)1024 * 512 * 2); // 1 MiB
    unsigned short* Db   = (unsigned short*)alloc((size_t)512 * 1024 * 2); // 1 MiB
    float* cb            = (float*)alloc(1024 * 4);
    float* ev            = (float*)alloc(512 * 4);
    unsigned short* QKb  = (unsigned short*)alloc((size_t)NB * 1024 * 2);  // 8 MiB
    unsigned short* G    = (unsigned short*)alloc((size_t)NB * 1024 * 2);  // 8 MiB
    float* gs            = (float*)alloc((size_t)NB * 4);

    k_prep_cd<<<263, 256, 0, stream>>>(Wq, bq, Wk, Wv, Wout, bv, bout,
                                       (const unsigned int*)mask,
                                       cb, ev, mode, Cb, Db);
    k_gemm_bt<0, 1><<<(4096 / 64) * (1024 / 64), 256, 0, stream>>>(
        src, Cb, QKb, cb, nullptr, nullptr, 4096, 1024, 512);
    k_attn<<<NB, 256, 0, stream>>>(gene, QKb, mask, mode, maskn, G, gs, aw);
    k_gemm_bt<1, 0><<<(4096 / 64) * (512 / 64), 256, 0, stream>>>(
        G, Db, out, ev, gs, src, 4096, 512, 1024);
}

// Round 2
// 450.126 us; speedup vs baseline: 1.0176x; 1.0176x over previous
//
#include <hip/hip_runtime.h>
#include <hip/hip_bf16.h>
#include <math.h>
#include <stdint.h>

// TGN attention node, algebraically restructured (K/V never materialized):
//   qk[b,h,:]  = C_h . source[b] + cb_h,   C = (1/16) Wk_h^T Wq_h   (bk cancels)
//   scores     = gene . qk, softmax over s
//   gbar[b,h]  = sum_s w[h,s] gene[b,s]    (sum w = 1 absorbs bv)
//   out        = ([gbar_0|gbar_1] @ D^T + e) * gate + residual,  D = Wout_h Wv_h
// Round 6: round-0 skeleton (srcb precompute, bf16-A GEMM, pure-streaming
// gene staging) + new k_attn score path: s-parallel LDS dot (8 lanes per
// neighbor slot, 3-level shfl reduce) replacing the MFMA detour. Removes one
// barrier, the sp[] buffer, and the 7/8-zero A-fragment MFMA work, while
// keeping the 256 MiB gene read a pure streaming loop. Ballot-based invalid
// handling kept from round 1.

#define NB 4096
#define SNB 32
#define DM 512

typedef __attribute__((ext_vector_type(8))) short bf16x8;
typedef __attribute__((ext_vector_type(4))) float f32x4;

__device__ __forceinline__ unsigned short f2bf(float f) {
    union { float f; unsigned int u; } v; v.f = f;
    unsigned int u = v.u;
    return (unsigned short)((u + 0x7FFFu + ((u >> 16) & 1u)) >> 16);
}
__device__ __forceinline__ float bf2f(unsigned short s) {
    union { unsigned int u; float f; } v; v.u = ((unsigned int)s) << 16;
    return v.f;
}

// ---------------- fused prep + C/D precompute -------------------------------
// blocks: [0] mask-dtype detect | [1,4] cb | [5,6] e | [7,262] src->bf16
//         [263,390] C tiles (MFMA, inline transpose) | [391,518] D tiles
__global__ __launch_bounds__(256) void k_prep_cd(
    const float* __restrict__ src, const float* __restrict__ Wq,
    const float* __restrict__ bq, const float* __restrict__ Wk,
    const float* __restrict__ Wv, const float* __restrict__ Wout,
    const float* __restrict__ bv, const float* __restrict__ bout,
    const unsigned int* __restrict__ maskw,
    unsigned short* __restrict__ srcb, float* __restrict__ cb,
    float* __restrict__ e, int* __restrict__ mode,
    unsigned short* __restrict__ C, unsigned short* __restrict__ D)
{
    __shared__ __align__(16) unsigned short As[64 * 40];
    __shared__ __align__(16) unsigned short Bs[64 * 40];
    __shared__ int fF, fH;
    int bid = blockIdx.x, t = threadIdx.x;

    if (bid == 0) {                                   // mask dtype detect
        if (t == 0) { fF = 0; fH = 0; }
        __syncthreads();
        int lf = 0, lh = 0;
        for (int i = t; i < 32768; i += 256) {        // 128KB: in-bounds u8/i32/f32
            unsigned int w = maskw[i];
            lf |= (w == 0x3F800000u);
            lh |= ((w & 0xFFFFFF00u) != 0u);
        }
        if (lf) atomicOr(&fF, 1);
        if (lh) atomicOr(&fH, 1);
        __syncthreads();
        if (t == 0) *mode = fF ? 2 : (fH ? 1 : 0);
        return;
    }
    if (bid <= 4) {                                   // cb[h*512+j] = Wk^T bq / 16
        int idx = (bid - 1) * 256 + t;
        int h = idx >> 9, j = idx & 511;
        float a = 0.f;
        for (int i = 0; i < 256; i++)
            a += Wk[(size_t)(h * 256 + i) * 512 + j] * bq[h * 256 + i];
        cb[idx] = 0.0625f * a;
        return;
    }
    if (bid <= 6) {                                   // e[n] = Wout.bv + bout
        int n = (bid - 5) * 256 + t;
        const float4* wr = (const float4*)(Wout + (size_t)n * 512);
        const float4* bv4 = (const float4*)bv;
        float a = bout[n];
        for (int q = 0; q < 128; q++) {
            float4 wv = wr[q], vv = bv4[q];
            a += wv.x * vv.x + wv.y * vv.y + wv.z * vv.z + wv.w * vv.w;
        }
        e[n] = a;
        return;
    }
    if (bid < 263) {                                  // source fp32->bf16
        int base = (bid - 7) * 2048;
        for (int q = 0; q < 8; q++) {
            int idx = base + q * 256 + t;
            float4 v = ((const float4*)src)[idx];
            ushort4 o;
            o.x = f2bf(v.x); o.y = f2bf(v.y); o.z = f2bf(v.z); o.w = f2bf(v.w);
            ((ushort4*)srcb)[idx] = o;
        }
        return;
    }

    // ---- C/D 64x64 MFMA tiles, K=256 (per-head), transpose during staging --
    int w = t >> 6, l = t & 63;
    int wm = (w >> 1) << 5, wn = (w & 1) << 5;
    int quad = l >> 4, lm = l & 15;
    int sj = t & 63, si8 = (t >> 6) << 3;             // transpose-staging map
    f32x4 acc00 = {0.f,0.f,0.f,0.f}, acc01 = {0.f,0.f,0.f,0.f};
    f32x4 acc10 = {0.f,0.f,0.f,0.f}, acc11 = {0.f,0.f,0.f,0.f};

    unsigned short* outp;
    int ldo;
    if (bid < 391) {                                  // C[j0..][m0..]
        int tt = bid - 263;
        int j0 = (tt >> 3) << 6, m0 = (tt & 7) << 6;
        int jc = j0 & 511;                            // Wk column (per-head j)
        int ib = (j0 >> 9) << 8;                      // head i-range base
        for (int ic = 0; ic < 8; ic++) {
            int i0 = ib + ic * 32;
            bf16x8 av, bw;
#pragma unroll
            for (int q = 0; q < 8; q++) {             // coalesced row-segment loads
                av[q] = (short)f2bf(Wk[(size_t)(i0 + si8 + q) * 512 + jc + sj] * 0.0625f);
                bw[q] = (short)f2bf(Wq[(size_t)(i0 + si8 + q) * 512 + m0 + sj]);
            }
            *(bf16x8*)(As + sj * 40 + si8) = av;      // transposed, conflict-free b128
            *(bf16x8*)(Bs + sj * 40 + si8) = bw;
            __syncthreads();
            bf16x8 a0 = *(const bf16x8*)(As + (wm + lm) * 40 + quad * 8);
            bf16x8 a1 = *(const bf16x8*)(As + (wm + 16 + lm) * 40 + quad * 8);
            bf16x8 b0 = *(const bf16x8*)(Bs + (wn + lm) * 40 + quad * 8);
            bf16x8 b1 = *(const bf16x8*)(Bs + (wn + 16 + lm) * 40 + quad * 8);
            acc00 = __builtin_amdgcn_mfma_f32_16x16x32_bf16(a0, b0, acc00, 0, 0, 0);
            acc01 = __builtin_amdgcn_mfma_f32_16x16x32_bf16(a0, b1, acc01, 0, 0, 0);
            acc10 = __builtin_amdgcn_mfma_f32_16x16x32_bf16(a1, b0, acc10, 0, 0, 0);
            acc11 = __builtin_amdgcn_mfma_f32_16x16x32_bf16(a1, b1, acc11, 0, 0, 0);
            __syncthreads();
        }
        outp = C + (size_t)j0 * 512 + m0; ldo = 512;
    } else {                                          // D[n0..][jh0..]
        int tt = bid - 391;
        int n0 = (tt >> 4) << 6, jh0 = (tt & 15) << 6;
        int jc0 = jh0 & 511;
        int ib = (jh0 >> 9) << 8;
        int ra = t >> 2, ca = (t & 3) << 3;           // direct-staging map (A)
        for (int ic = 0; ic < 8; ic++) {
            int i0 = ib + ic * 32;
            {                                         // A = Wout rows (no transpose)
                const float4* p = (const float4*)(Wout + (size_t)(n0 + ra) * 512 + i0 + ca);
                float4 v0 = p[0], v1 = p[1];
                bf16x8 av;
                av[0] = (short)f2bf(v0.x); av[1] = (short)f2bf(v0.y);
                av[2] = (short)f2bf(v0.z); av[3] = (short)f2bf(v0.w);
                av[4] = (short)f2bf(v1.x); av[5] = (short)f2bf(v1.y);
                av[6] = (short)f2bf(v1.z); av[7] = (short)f2bf(v1.w);
                *(bf16x8*)(As + ra * 40 + ca) = av;
            }
            bf16x8 bw;
#pragma unroll
            for (int q = 0; q < 8; q++)               // B = Wv^T via transpose staging
                bw[q] = (short)f2bf(Wv[(size_t)(i0 + si8 + q) * 512 + jc0 + sj]);
            *(bf16x8*)(Bs + sj * 40 + si8) = bw;
            __syncthreads();
            bf16x8 a0 = *(const bf16x8*)(As + (wm + lm) * 40 + quad * 8);
            bf16x8 a1 = *(const bf16x8*)(As + (wm + 16 + lm) * 40 + quad * 8);
            bf16x8 b0 = *(const bf16x8*)(Bs + (wn + lm) * 40 + quad * 8);
            bf16x8 b1 = *(const bf16x8*)(Bs + (wn + 16 + lm) * 40 + quad * 8);
            acc00 = __builtin_amdgcn_mfma_f32_16x16x32_bf16(a0, b0, acc00, 0, 0, 0);
            acc01 = __builtin_amdgcn_mfma_f32_16x16x32_bf16(a0, b1, acc01, 0, 0, 0);
            acc10 = __builtin_amdgcn_mfma_f32_16x16x32_bf16(a1, b0, acc10, 0, 0, 0);
            acc11 = __builtin_amdgcn_mfma_f32_16x16x32_bf16(a1, b1, acc11, 0, 0, 0);
            __syncthreads();
        }
        outp = D + (size_t)n0 * 1024 + jh0; ldo = 1024;
    }
    f32x4 accs[2][2] = {{acc00, acc01}, {acc10, acc11}};
    for (int ms = 0; ms < 2; ms++)
        for (int ns = 0; ns < 2; ns++)
            for (int r = 0; r < 4; r++)
                outp[(size_t)(wm + ms * 16 + quad * 4 + r) * ldo + wn + ns * 16 + lm] =
                    f2bf(accs[ms][ns][r]);
}

// ---------------- MFMA GEMM, B^T layout, BK=64: out[m,n]=sum_k A[m,k]Bt[n,k]
// EPI 0: bf16 out = acc + bias[n]  (QK)
// EPI 1: f32 out = (acc + bias[n]) * gscale[m] + resid[m,n]  (final)
template <int EPI>
__global__ __launch_bounds__(256) void k_gemm_bt(
    const unsigned short* __restrict__ A, const unsigned short* __restrict__ Bt,
    void* __restrict__ outp, const float* __restrict__ bias,
    const float* __restrict__ gscale, const float* __restrict__ resid,
    int M, int N, int K)
{
    __shared__ __align__(16) unsigned short As[2][64 * 40];
    __shared__ __align__(16) unsigned short Bs[2][64 * 40];
    int nt = N >> 6;
    int m0 = ((int)blockIdx.x / nt) << 6;
    int n0 = ((int)blockIdx.x % nt) << 6;
    int t = threadIdx.x;
    int w = t >> 6, l = t & 63;
    int wm = (w >> 1) << 5, wn = (w & 1) << 5;
    int quad = l >> 4, lm = l & 15;

    f32x4 acc00 = {0.f,0.f,0.f,0.f}, acc01 = {0.f,0.f,0.f,0.f};
    f32x4 acc10 = {0.f,0.f,0.f,0.f}, acc11 = {0.f,0.f,0.f,0.f};

    int srow = t >> 2, spart = t & 3;
    int chunk = spart >> 1, coff = (spart & 1) << 4;
    const unsigned short* ag = A + (size_t)(m0 + srow) * K + spart * 16;
    const unsigned short* bg = Bt + (size_t)(n0 + srow) * K + spart * 16;
    unsigned short* asl = &As[chunk][srow * 40 + coff];
    unsigned short* bsl = &Bs[chunk][srow * 40 + coff];

    for (int k0 = 0; k0 < K; k0 += 64) {
        *(bf16x8*)asl       = *(const bf16x8*)ag;
        *(bf16x8*)(asl + 8) = *(const bf16x8*)(ag + 8);
        *(bf16x8*)bsl       = *(const bf16x8*)bg;
        *(bf16x8*)(bsl + 8) = *(const bf16x8*)(bg + 8);
        ag += 64; bg += 64;
        __syncthreads();
#pragma unroll
        for (int c = 0; c < 2; c++) {
            bf16x8 a0 = *(const bf16x8*)(&As[c][(wm + lm) * 40 + quad * 8]);
            bf16x8 a1 = *(const bf16x8*)(&As[c][(wm + 16 + lm) * 40 + quad * 8]);
            bf16x8 b0 = *(const bf16x8*)(&Bs[c][(wn + lm) * 40 + quad * 8]);
            bf16x8 b1 = *(const bf16x8*)(&Bs[c][(wn + 16 + lm) * 40 + quad * 8]);
            acc00 = __builtin_amdgcn_mfma_f32_16x16x32_bf16(a0, b0, acc00, 0, 0, 0);
            acc01 = __builtin_amdgcn_mfma_f32_16x16x32_bf16(a0, b1, acc01, 0, 0, 0);
            acc10 = __builtin_amdgcn_mfma_f32_16x16x32_bf16(a1, b0, acc10, 0, 0, 0);
            acc11 = __builtin_amdgcn_mfma_f32_16x16x32_bf16(a1, b1, acc11, 0, 0, 0);
        }
        __syncthreads();
    }
    f32x4 accs[2][2] = {{acc00, acc01}, {acc10, acc11}};
    for (int ms = 0; ms < 2; ms++) {
        for (int ns = 0; ns < 2; ns++) {
            int n = n0 + wn + ns * 16 + lm;
            float bval = bias[n];
            for (int r = 0; r < 4; r++) {
                int m = m0 + wm + ms * 16 + quad * 4 + r;
                float v = accs[ms][ns][r] + bval;
                if (EPI == 0) {
                    ((unsigned short*)outp)[(size_t)m * N + n] = f2bf(v);
                } else {
                    ((float*)outp)[(size_t)m * N + n] =
                        v * gscale[m] + resid[(size_t)m * N + n];
                }
            }
        }
    }
}

// ---------------- fused per-row attention -----------------------------------
// Pure-streaming gene staging; scores via s-parallel LDS dot (8 lanes per
// neighbor slot, 3-level shfl reduce); ballot-based invalid handling.
__global__ __launch_bounds__(256) void k_attn(
    const float* __restrict__ gene, const unsigned short* __restrict__ QKb,
    const void* __restrict__ maskbuf, const int* __restrict__ modep,
    const float* __restrict__ mask_n,
    unsigned short* __restrict__ G, float* __restrict__ gscale,
    float* __restrict__ aw_out)
{
    __shared__ __align__(16) unsigned short glb[32 * 520];
    __shared__ __align__(16) unsigned short qs[1024];
    __shared__ float sc[64];                          // [h*32 + s]
    __shared__ float wls[64];

    int b = blockIdx.x, t = threadIdx.x;
    int w = t >> 6, l = t & 63;

    // hoisted mask load (latency hides under gene loads)
    int mode = *modep;
    int mk = 0;
    if (t < 64) {
        size_t moff = (size_t)b * 32 + (t & 31);
        if (mode == 1)      mk = ((const unsigned char*)maskbuf)[moff] != 0;
        else if (mode == 2) mk = (((const float*)maskbuf)[moff] != 0.0f);
        else                mk = (((const int*)maskbuf)[moff] != 0);
    }

    // qk row (both heads, bf16) -> LDS
    *(ushort4*)(qs + t * 4) = *(const ushort4*)(QKb + (size_t)b * 1024 + t * 4);

    // stage gene -> LDS bf16 (pure streaming, no interleaved reductions)
    const float4* gp = (const float4*)(gene + (size_t)b * (SNB * DM));
#pragma unroll
    for (int it = 0; it < 8; it++) {
        float4 v0 = gp[t * 2 + it * 512];
        float4 v1 = gp[t * 2 + 1 + it * 512];
        int s = w + it * 4;
        bf16x8 pk;
        pk[0] = (short)f2bf(v0.x); pk[1] = (short)f2bf(v0.y);
        pk[2] = (short)f2bf(v0.z); pk[3] = (short)f2bf(v0.w);
        pk[4] = (short)f2bf(v1.x); pk[5] = (short)f2bf(v1.y);
        pk[6] = (short)f2bf(v1.z); pk[7] = (short)f2bf(v1.w);
        *(bf16x8*)(glb + s * 520 + l * 8) = pk;
    }
    __syncthreads();

    // scores: s = t>>3 (32 slots), u = t&7 handles dims u*8 + k*64
    {
        int s = t >> 3, u = t & 7;
        float p0 = 0.f, p1 = 0.f;
#pragma unroll
        for (int k = 0; k < 8; k++) {
            int d = k * 64 + u * 8;
            bf16x8 gv = *(const bf16x8*)(glb + s * 520 + d);
            bf16x8 q0 = *(const bf16x8*)(qs + d);
            bf16x8 q1 = *(const bf16x8*)(qs + 512 + d);
#pragma unroll
            for (int j = 0; j < 8; j++) {
                float g = bf2f((unsigned short)gv[j]);
                p0 += g * bf2f((unsigned short)q0[j]);
                p1 += g * bf2f((unsigned short)q1[j]);
            }
        }
        p0 += __shfl_xor(p0, 4, 64); p1 += __shfl_xor(p1, 4, 64);
        p0 += __shfl_xor(p0, 2, 64); p1 += __shfl_xor(p1, 2, 64);
        p0 += __shfl_xor(p0, 1, 64); p1 += __shfl_xor(p1, 1, 64);
        if (u == 0) { sc[s] = p0; sc[32 + s] = p1; }
    }
    __syncthreads();

    // softmax (wave 0: lanes 0..31 = h0, 32..63 = h1; same s pattern per half)
    if (t < 64) {
        unsigned long long bal = __ballot(mk != 0);
        int invalid = (bal == 0xFFFFFFFFFFFFFFFFull);
        if (invalid && (t & 31) == 0) mk = 0;         // unmask slot 0
        float v = sc[t];
        float vm = mk ? -1e30f : v;
        for (int off = 16; off > 0; off >>= 1) vm = fmaxf(vm, __shfl_xor(vm, off, 64));
        float ex = mk ? 0.0f : __expf(v - vm);
        float sm = ex;
        for (int off = 16; off > 0; off >>= 1) sm += __shfl_xor(sm, off, 64);
        wls[t] = ex / sm;
        if (t == 0) gscale[b] = invalid ? 0.0f : mask_n[b];
    }
    __syncthreads();

    if (t < 32) aw_out[(size_t)b * 32 + t] = 0.5f * (wls[t] + wls[32 + t]);

    // PV: gbar[h, jg..jg+3] = sum_s w[h,s] * gene[s, jg..jg+3]
    {
        int h = t >> 7, jg = (t & 127) << 2;
        float a0 = 0.f, a1 = 0.f, a2 = 0.f, a3 = 0.f;
        const float* wrow = wls + h * 32;
        for (int s4 = 0; s4 < 8; s4++) {
            float4 wv = *(const float4*)(wrow + s4 * 4);
#pragma unroll
            for (int si = 0; si < 4; si++) {
                int s = s4 * 4 + si;
                ushort4 gv = *(const ushort4*)(glb + s * 520 + jg);
                float wq = (si == 0) ? wv.x : (si == 1) ? wv.y : (si == 2) ? wv.z : wv.w;
                a0 += wq * bf2f(gv.x); a1 += wq * bf2f(gv.y);
                a2 += wq * bf2f(gv.z); a3 += wq * bf2f(gv.w);
            }
        }
        ushort4 ov;
        ov.x = f2bf(a0); ov.y = f2bf(a1); ov.z = f2bf(a2); ov.w = f2bf(a3);
        *(ushort4*)(G + (size_t)b * 1024 + h * 512 + jg) = ov;
    }
}

extern "C" void kernel_launch(void* const* d_in, const int* in_sizes, int n_in,
                              void* d_out, int out_size, void* d_ws, size_t ws_size,
                              hipStream_t stream)
{
    const float* src   = (const float*)d_in[0];
    const float* gene  = (const float*)d_in[1];
    const void*  mask  = d_in[2];
    const float* maskn = (const float*)d_in[3];
    const float* Wq    = (const float*)d_in[4];
    const float* bq    = (const float*)d_in[5];
    const float* Wk    = (const float*)d_in[6];
    // d_in[7] = bk: cancels in softmax, unused
    const float* Wv    = (const float*)d_in[8];
    const float* bv    = (const float*)d_in[9];
    const float* Wout  = (const float*)d_in[10];
    const float* bout  = (const float*)d_in[11];

    float* out = (float*)d_out;
    float* aw  = out + (size_t)NB * DM;

    char* ws = (char*)d_ws;
    size_t off = 0;
    auto alloc = [&](size_t bytes) -> void* {
        void* p = ws + off;
        off = (off + bytes + 255) & ~((size_t)255);
        return p;
    };
    int* mode            = (int*)alloc(4);
    unsigned short* srcb = (unsigned short*)alloc((size_t)NB * DM * 2);    // 4 MiB
    unsigned short* Cb   = (unsigned short*)alloc((size_t)1024 * 512 * 2); // 1 MiB
    unsigned short* Db   = (unsigned short*)alloc((size_t)512 * 1024 * 2); // 1 MiB
    float* cb            = (float*)alloc(1024 * 4);
    float* ev            = (float*)alloc(512 * 4);
    unsigned short* QKb  = (unsigned short*)alloc((size_t)NB * 1024 * 2);  // 8 MiB
    unsigned short* G    = (unsigned short*)alloc((size_t)NB * 1024 * 2);  // 8 MiB
    float* gs            = (float*)alloc((size_t)NB * 4);

    k_prep_cd<<<519, 256, 0, stream>>>(src, Wq, bq, Wk, Wv, Wout, bv, bout,
                                       (const unsigned int*)mask,
                                       srcb, cb, ev, mode, Cb, Db);
    k_gemm_bt<0><<<(4096 / 64) * (1024 / 64), 256, 0, stream>>>(
        srcb, Cb, QKb, cb, nullptr, nullptr, 4096, 1024, 512);
    k_attn<<<NB, 256, 0, stream>>>(gene, QKb, mask, mode, maskn, G, gs, aw);
    k_gemm_bt<1><<<(4096 / 64) * (512 / 64), 256, 0, stream>>>(
        G, Db, out, ev, gs, src, 4096, 512, 1024);
}